// Round 1
// baseline (323.381 us; speedup 1.0000x reference)
//
#include <hip/hip_runtime.h>

// ReservoirSampler WITHOUT d_ws.
//
// Why: rocprof shows the timed path dominated by ~165 us 1 GiB
// __amd_rocclr_fillBufferAligned dispatches (80% HBM peak) — the harness's
// workspace re-poison, which the previous kernel *required* (winner init via
// 0xAA poison). The actual algorithm moves ~34 MB ≈ 6 us. Eliminating all
// d_ws usage removes the poison fill from the timed iteration.
//
// The winner table (n int32 = 64 KiB) lives in a scratch region of d_out:
// out rows [0, head_rows) where head_rows = ceil(n/256) = 64 (each 1 KiB out
// row holds 256 int32). Kernel order (stream-serialized):
//   K0 rs_init        : wtab[0..n) = -1            (wtab aliases out)
//   K1 rs_scatter     : atomicMax(wtab[ri], p) for reservoir-phase accepts
//   K2 rs_gather_main : writes out rows [head_rows, n); reads wtab bytes it
//                       never writes (wtab lives entirely in rows < head_rows)
//   K3 rs_gather_head : ONE block; stages wtab[0..head_rows) into LDS,
//                       __syncthreads, then overwrites the scratch rows with
//                       their true output. Read-before-write within the block.
// Replay-idempotent: K0 re-inits the scratch every graph replay; K1 atomicMax
// over identical inputs is a deterministic fixed point; K2/K3 pure functions
// of (wtab, inputs). No dependence on any pre-call memory state.
//
// Index math matches numpy bit-exactly: r = floor(u * (pos+1)) in plain f32 RN
// (pos+1 < 2^24, exact), clipped to pos, accepted iff < n.
// Fill-vs-reservoir priority: a reservoir write to slot s has p >= n-i0, a
// fill write to s has p = s-i0 < n-i0, so winner>=0 always wins (max p).

#define D_FEAT 256
#define F4_PER_ROW (D_FEAT / 4)   // 64 float4 per 1 KiB row
#define INTS_PER_ROW D_FEAT       // 256 int32 per out row

__global__ void rs_init(int* wtab, int n) {
    const int i = blockIdx.x * blockDim.x + threadIdx.x;
    if (i < n) wtab[i] = -1;
}

__global__ void rs_scatter(const float* __restrict__ u,
                           const int* __restrict__ i0_ptr,
                           int* wtab, int b, int n) {
    const int p = blockIdx.x * blockDim.x + threadIdx.x;
    if (p >= b) return;
    const int pos = *i0_ptr + p;
    if (pos < n) return;                 // fill phase handled by gather default
    float r = floorf(u[p] * (float)(pos + 1));
    int ri = (int)r;
    if (ri > pos) ri = pos;              // clip u -> 1
    if (ri >= n) return;                 // rejected
    atomicMax(&wtab[ri], p);             // device-scope, cross-XCD safe
}

__device__ __forceinline__ const float4* rs_src(const float4* samples,
                                                const float4* buffer,
                                                int w, int row, int i0, int b) {
    if (w >= 0)                    return samples + (size_t)w * F4_PER_ROW;   // reservoir winner
    if (row >= i0 && row - i0 < b) return samples + (size_t)(row - i0) * F4_PER_ROW; // fill write
    return buffer + (size_t)row * F4_PER_ROW;                                 // untouched
}

// Rows [head_rows, n): one 64-lane wave per 1 KiB row, float4 coalesced.
// wtab reads hit bytes inside rows [0, head_rows) which this kernel never
// writes -> no alias hazard (wtab/out intentionally NOT __restrict__).
__global__ void rs_gather_main(const float4* __restrict__ samples,
                               const float4* __restrict__ buffer,
                               const int* __restrict__ i0_ptr,
                               const int* wtab,
                               float4* out, int b, int n, int head_rows) {
    const int row  = head_rows + blockIdx.x * 4 + (threadIdx.x >> 6);
    const int lane = threadIdx.x & 63;
    if (row >= n) return;
    const int i0 = *i0_ptr;
    const int w  = wtab[row];            // wave-uniform
    const float4* src = rs_src(samples, buffer, w, row, i0, b);
    out[(size_t)row * F4_PER_ROW + lane] = src[lane];
}

// Rows [0, head_rows): single block. Stage winners in LDS before overwriting
// the scratch region they live in.
__global__ void rs_gather_head(const float4* __restrict__ samples,
                               const float4* __restrict__ buffer,
                               const int* __restrict__ i0_ptr,
                               const int* wtab,
                               float4* out, int b, int n, int head_rows) {
    __shared__ int sw[256];              // head_rows <= 256 (n <= 65536)
    const int tid = threadIdx.x;
    if (tid < head_rows) sw[tid] = wtab[tid];
    __syncthreads();
    const int i0 = *i0_ptr;
    const int total = head_rows * F4_PER_ROW;        // 4096 f4 stores @ n=16384
    for (int e = tid; e < total; e += blockDim.x) {
        const int row  = e >> 6;         // wave-uniform per 64-thread group
        const int lane = e & 63;
        const float4* src = rs_src(samples, buffer, sw[row], row, i0, b);
        out[(size_t)row * F4_PER_ROW + lane] = src[lane];
    }
}

extern "C" void kernel_launch(void* const* d_in, const int* in_sizes, int n_in,
                              void* d_out, int out_size, void* d_ws, size_t ws_size,
                              hipStream_t stream) {
    (void)d_ws; (void)ws_size; (void)n_in; (void)out_size;   // d_ws deliberately unused

    const float4* samples = (const float4*)d_in[0];
    const float4* buffer  = (const float4*)d_in[1];
    const float*  u       = (const float*)d_in[2];
    const int*    i0_ptr  = (const int*)d_in[3];
    float4*       out     = (float4*)d_out;

    const int b = in_sizes[0] / D_FEAT;   // 262144
    const int n = in_sizes[1] / D_FEAT;   // 16384

    const int head_rows = (n + INTS_PER_ROW - 1) / INTS_PER_ROW;  // 64
    int* wtab = (int*)d_out;              // n int32 in out rows [0, head_rows)

    rs_init<<<(n + 255) / 256, 256, 0, stream>>>(wtab, n);
    rs_scatter<<<(b + 255) / 256, 256, 0, stream>>>(u, i0_ptr, wtab, b, n);
    rs_gather_main<<<((n - head_rows) + 3) / 4, 256, 0, stream>>>(
        samples, buffer, i0_ptr, wtab, out, b, n, head_rows);
    rs_gather_head<<<1, 1024, 0, stream>>>(
        samples, buffer, i0_ptr, wtab, out, b, n, head_rows);
}